// Round 10
// baseline (183.898 us; speedup 1.0000x reference)
//
#include <hip/hip_runtime.h>
#include <hip/hip_fp16.h>

#define IN_DIM 128
#define HID 64
#define BKT 64            // nodes per bucket
#define NBMAX 1024        // max buckets (N <= 65536)
#define SLACK 2048        // binned capacity per bucket (mean ~1279, >20 sigma)
#define BM 64             // gemm rows per block
#define CHUNKMAX 4096     // bin: max edges cached per block (16 KB LDS)

// Bin edges by 64-node dst bucket, converting from raw (int64|int32) edge_index on the fly.
// int64-detect per-block (reads first 256 int32 words; odd words all zero => int64).
// Entry = (src << 6) | (dst & 63). Per-block LDS histogram -> one global reservation per
// (block,bucket) into zero-initialized bcnt -> direct writes; consecutive slots claimed by
// the same block -> L2 write-combined. Pass 1 caches converted dst in LDS.
__global__ __launch_bounds__(512) void bin_kernel(const void* ei, int E, int NB,
                                                  int* bcnt, int* __restrict__ binned) {
    __shared__ int lhist[NBMAX];
    __shared__ int lbase[NBMAX];
    __shared__ int dcache[CHUNKMAX];
    __shared__ int sflag;
    int t = threadIdx.x;
    if (t < 64) {
        const int* ei32 = (const int*)ei;
        int nz = (ei32[2 * t + 1] != 0) | (ei32[2 * (t + 64) + 1] != 0);
        unsigned long long bl = __ballot(nz);
        if (t == 0) sflag = (bl == 0ULL) ? 1 : 0;
    }
    for (int b = t; b < NBMAX; b += 512) lhist[b] = 0;
    __syncthreads();
    bool w64 = sflag != 0;
    int chunk = (E + gridDim.x - 1) / gridDim.x;
    int cs = blockIdx.x * chunk;
    int ce = cs + chunk; if (ce > E) ce = E;
    for (int i = cs + t; i < ce; i += 512) {
        int d = w64 ? (int)((const long long*)ei)[E + i] : ((const int*)ei)[E + i];
        int j = i - cs;
        if (j < CHUNKMAX) dcache[j] = d;
        atomicAdd(&lhist[d >> 6], 1);
    }
    __syncthreads();
    for (int b = t; b < NB; b += 512) {
        int c = lhist[b];
        if (c) lbase[b] = b * SLACK + atomicAdd(&bcnt[b], c);
        lhist[b] = 0;  // reuse as local cursor
    }
    __syncthreads();
    for (int i = cs + t; i < ce; i += 512) {
        int s = w64 ? (int)((const long long*)ei)[i] : ((const int*)ei)[i];
        int j = i - cs;
        int d = (j < CHUNKMAX) ? dcache[j]
                               : (w64 ? (int)((const long long*)ei)[E + i] : ((const int*)ei)[E + i]);
        int b = d >> 6;
        int p = lbase[b] + atomicAdd(&lhist[b], 1);
        binned[p] = (s << 6) | (d & 63);
    }
}

// Sort within bucket (block-per-bucket). Inline exclusive prefix over bcnt[0..b) (L2-hot).
// LDS 64-counter histogram + wave scan produce exact CSR, off[v], dinv[v]=rsqrt(deg+1).
__global__ __launch_bounds__(256) void sort_kernel(const int* __restrict__ binned,
                                                   const int* __restrict__ bcnt, int N, int E,
                                                   int* __restrict__ off, float* __restrict__ dinv,
                                                   int* __restrict__ csr) {
    __shared__ int hist[BKT];
    __shared__ int cur[BKT];
    __shared__ int pred[4];
    int t = threadIdx.x;
    int b = blockIdx.x;
    int v0 = b * BKT;
    int part = 0;
    for (int j = t; j < b; j += 256) part += bcnt[j];
#pragma unroll
    for (int o = 32; o > 0; o >>= 1) part += __shfl_down(part, o, 64);
    if ((t & 63) == 0) pred[t >> 6] = part;
    if (t < BKT) hist[t] = 0;
    __syncthreads();
    int base = pred[0] + pred[1] + pred[2] + pred[3];
    int cnt_b = bcnt[b];                 // broadcast load
    int si = b * SLACK, ei_ = si + cnt_b;
    for (int i = si + t; i < ei_; i += 256) atomicAdd(&hist[binned[i] & 63], 1);
    __syncthreads();
    if (t < 64) {                        // wave 0: exclusive scan of 64 counters
        int c = hist[t];
        int sc = c;
#pragma unroll
        for (int o = 1; o < 64; o <<= 1) {
            int y = __shfl_up(sc, o, 64);
            if (t >= o) sc += y;
        }
        int start = base + sc - c;
        cur[t] = start;
        int v = v0 + t;
        if (v < N) {
            off[v] = start;
            dinv[v] = rsqrtf((float)(c + 1));
        }
    }
    if (b == 0 && t == 64) off[N] = E;
    __syncthreads();
    for (int i = si + t; i < ei_; i += 256) {
        int a = binned[i];
        int p = atomicAdd(&cur[a & 63], 1);
        csr[p] = a >> 6;
    }
}

// g1 = fp16( dinv ⊙ (x @ W1) ).  W-in-registers: each lane owns W column `lane`
// (128 statically-indexed VGPRs). x rows staged in LDS, read as wave-uniform b128
// broadcasts -> FMA-bound.
__global__ __launch_bounds__(256) void gemm1_kernel(const float* __restrict__ x, const float* __restrict__ W1,
                                                    const float* __restrict__ dinv, __half* __restrict__ g1, int N) {
    __shared__ float xs[BM * IN_DIM];    // 32 KB = 2048 float4
    int t = threadIdx.x;
    int lane = t & 63, wv = t >> 6;
    int row0 = blockIdx.x * BM;
    float wreg[IN_DIM];
#pragma unroll
    for (int k = 0; k < IN_DIM; ++k) wreg[k] = W1[k * HID + lane];   // coalesced 256B/instr
#pragma unroll
    for (int p = 0; p < 8; ++p) {
        int id = t + 256 * p;            // id = r*32 + g
        int r = id >> 5, g = id & 31;
        float4 v = make_float4(0.f, 0.f, 0.f, 0.f);
        int gr = row0 + r;
        if (gr < N) v = ((const float4*)x)[(size_t)gr * (IN_DIM / 4) + g];
        ((float4*)xs)[id] = v;
    }
    __syncthreads();
    const float4* xs4 = (const float4*)xs;
    for (int rr = 0; rr < 16; ++rr) {
        int r = wv * 16 + rr;
        float acc = 0.f;
#pragma unroll
        for (int k4 = 0; k4 < 32; ++k4) {
            float4 xv = xs4[r * 32 + k4];            // wave-uniform broadcast
            acc = fmaf(xv.x, wreg[4 * k4 + 0], acc);
            acc = fmaf(xv.y, wreg[4 * k4 + 1], acc);
            acc = fmaf(xv.z, wreg[4 * k4 + 2], acc);
            acc = fmaf(xv.w, wreg[4 * k4 + 3], acc);
        }
        int gr = row0 + r;
        if (gr < N) g1[(size_t)gr * HID + lane] = __float2half(dinv[gr] * acc);
    }
}

// Layer-1 aggregation, dual-edge packed: lanes 0-31 process the even edge of each pair,
// lanes 32-63 the odd edge; each lane loads a __half2 (features 2*sub, 2*sub+1).
// One VMEM instruction covers TWO edges (2x fewer row loads, 16 edges in flight).
// Cross-half combine via 2 shfl_down, then half-wave epilogue: relu + W2 dot -> g2.
__global__ __launch_bounds__(256) void gather1_kernel(const __half* __restrict__ g1, const int* __restrict__ off,
                                                      const int* __restrict__ csr, const float* __restrict__ dinv,
                                                      const float* __restrict__ b1, const float* __restrict__ W2,
                                                      float* __restrict__ g2, int N) {
    int wid = threadIdx.x >> 6;
    int lane = threadIdx.x & 63;
    int v = blockIdx.x * 4 + wid;
    if (v >= N) return;
    bool hi = lane >= 32;
    int sub = lane & 31;
    const __half2* g1h2 = (const __half2*)g1;   // row stride 32 half2
    int s = off[v], e = off[v + 1];
    float2 acc = make_float2(0.f, 0.f);
    if (!hi) {                                   // self loop on lo half
        float2 f = __half22float2(g1h2[(size_t)v * 32 + sub]);
        acc.x += f.x; acc.y += f.y;
    }
    int i = s;
    while (i < e && (i & 3)) {                   // align csr to 16B; lo half only
        if (!hi) {
            float2 f = __half22float2(g1h2[(size_t)csr[i] * 32 + sub]);
            acc.x += f.x; acc.y += f.y;
        }
        ++i;
    }
    for (; i + 16 <= e; i += 16) {               // 8 paired loads = 16 edges in flight
        int4 a = *(const int4*)(csr + i);
        int4 b = *(const int4*)(csr + i + 4);
        int4 c = *(const int4*)(csr + i + 8);
        int4 d = *(const int4*)(csr + i + 12);
        int u0 = hi ? a.y : a.x, u1 = hi ? a.w : a.z;
        int u2 = hi ? b.y : b.x, u3 = hi ? b.w : b.z;
        int u4 = hi ? c.y : c.x, u5 = hi ? c.w : c.z;
        int u6 = hi ? d.y : d.x, u7 = hi ? d.w : d.z;
        float2 f0 = __half22float2(g1h2[(size_t)u0 * 32 + sub]);
        float2 f1 = __half22float2(g1h2[(size_t)u1 * 32 + sub]);
        float2 f2 = __half22float2(g1h2[(size_t)u2 * 32 + sub]);
        float2 f3 = __half22float2(g1h2[(size_t)u3 * 32 + sub]);
        float2 f4 = __half22float2(g1h2[(size_t)u4 * 32 + sub]);
        float2 f5 = __half22float2(g1h2[(size_t)u5 * 32 + sub]);
        float2 f6 = __half22float2(g1h2[(size_t)u6 * 32 + sub]);
        float2 f7 = __half22float2(g1h2[(size_t)u7 * 32 + sub]);
        acc.x += ((f0.x + f1.x) + (f2.x + f3.x)) + ((f4.x + f5.x) + (f6.x + f7.x));
        acc.y += ((f0.y + f1.y) + (f2.y + f3.y)) + ((f4.y + f5.y) + (f6.y + f7.y));
    }
    for (; i + 2 <= e; i += 2) {                 // pair tail
        int u = hi ? csr[i + 1] : csr[i];
        float2 f = __half22float2(g1h2[(size_t)u * 32 + sub]);
        acc.x += f.x; acc.y += f.y;
    }
    if (i < e && !hi) {                          // odd single tail, lo half only
        float2 f = __half22float2(g1h2[(size_t)csr[i] * 32 + sub]);
        acc.x += f.x; acc.y += f.y;
    }
    // combine hi half into lo half
    acc.x += __shfl_down(acc.x, 32, 64);
    acc.y += __shfl_down(acc.y, 32, 64);
    // epilogue on lanes 0-31 (hi lanes compute garbage, never written)
    float dv = dinv[v];
    float2 b1v = ((const float2*)b1)[sub];
    float2 w2v = ((const float2*)W2)[sub];
    float hx = fmaxf(fmaf(dv, acc.x, b1v.x), 0.0f);
    float hy = fmaxf(fmaf(dv, acc.y, b1v.y), 0.0f);
    float p = fmaf(hx, w2v.x, hy * w2v.y);
#pragma unroll
    for (int o = 16; o > 0; o >>= 1) p += __shfl_down(p, o, 64);
    if (lane == 0) g2[v] = dv * p;
}

// Layer-2 aggregation on scalars: out[v] = dinv[v]*(g2[v] + sum g2[u]) + b2
__global__ __launch_bounds__(256) void gather2_kernel(const float* __restrict__ g2, const int* __restrict__ off,
                                                      const int* __restrict__ csr, const float* __restrict__ dinv,
                                                      const float* __restrict__ b2, float* __restrict__ out, int N) {
    int wid = threadIdx.x >> 6;
    int lane = threadIdx.x & 63;
    int v = blockIdx.x * 4 + wid;
    if (v >= N) return;
    int s = off[v], e = off[v + 1];
    float p = 0.f;
    for (int i = s + lane; i < e; i += 64) p += g2[csr[i]];
#pragma unroll
    for (int o = 32; o > 0; o >>= 1) p += __shfl_down(p, o, 64);
    if (lane == 0) out[v] = fmaf(dinv[v], g2[v] + p, b2[0]);
}

extern "C" void kernel_launch(void* const* d_in, const int* in_sizes, int n_in,
                              void* d_out, int out_size, void* d_ws, size_t ws_size,
                              hipStream_t stream) {
    const float* x  = (const float*)d_in[0];
    const void*  ei = d_in[1];
    const float* W1 = (const float*)d_in[2];
    const float* b1 = (const float*)d_in[3];
    const float* W2 = (const float*)d_in[4];
    const float* b2 = (const float*)d_in[5];
    float* out = (float*)d_out;

    int N = in_sizes[0] / IN_DIM;
    int E = in_sizes[1] / 2;
    int NB = (N + BKT - 1) / BKT;   // 782 for N=50000 (<= NBMAX)

    char* w = (char*)d_ws;
    size_t o = 0;
    auto alloc = [&](size_t bytes) { char* p = w + o; o = (o + bytes + 255) & ~(size_t)255; return p; };
    int*    bcnt   = (int*)   alloc((size_t)NBMAX * sizeof(int));
    int*    off    = (int*)   alloc((size_t)(N + 1) * sizeof(int));
    float*  dinv   = (float*) alloc((size_t)N * sizeof(float));
    int*    binned = (int*)   alloc((size_t)NB * SLACK * sizeof(int));
    int*    csr    = (int*)   alloc((size_t)E * sizeof(int));
    __half* g1     = (__half*)alloc((size_t)N * HID * sizeof(__half));
    float*  g2     = (float*) alloc((size_t)N * sizeof(float));
    (void)ws_size; (void)n_in; (void)out_size;

    hipMemsetAsync(bcnt, 0, (size_t)NBMAX * sizeof(int), stream);
    bin_kernel<<<256, 512, 0, stream>>>(ei, E, NB, bcnt, binned);
    sort_kernel<<<NB, 256, 0, stream>>>(binned, bcnt, N, E, off, dinv, csr);
    gemm1_kernel<<<(N + BM - 1) / BM, 256, 0, stream>>>(x, W1, dinv, g1, N);
    gather1_kernel<<<(N + 3) / 4, 256, 0, stream>>>(g1, off, csr, dinv, b1, W2, g2, N);
    gather2_kernel<<<(N + 3) / 4, 256, 0, stream>>>(g2, off, csr, dinv, b2, out, N);
}

// Round 11
// 179.143 us; speedup vs baseline: 1.0265x; 1.0265x over previous
//
#include <hip/hip_runtime.h>
#include <hip/hip_fp16.h>

#define IN_DIM 128
#define HID 64
#define BKT 64            // nodes per bucket
#define NBMAX 1024        // max buckets (N <= 65536)
#define SLACK 2048        // binned capacity per bucket (mean ~1279, >20 sigma)
#define BM 64             // gemm rows per block
#define CHUNKMAX 4096     // bin: max edges cached per block (16 KB LDS)

// Bin edges by 64-node dst bucket, converting from raw (int64|int32) edge_index on the fly.
// int64-detect per-block (reads first 256 int32 words; odd words all zero => int64).
// Entry = (src << 6) | (dst & 63). Per-block LDS histogram -> one global reservation per
// (block,bucket) into zero-initialized bcnt -> direct writes; consecutive slots claimed by
// the same block -> L2 write-combined. Pass 1 caches converted dst in LDS.
__global__ __launch_bounds__(512) void bin_kernel(const void* ei, int E, int NB,
                                                  int* bcnt, int* __restrict__ binned) {
    __shared__ int lhist[NBMAX];
    __shared__ int lbase[NBMAX];
    __shared__ int dcache[CHUNKMAX];
    __shared__ int sflag;
    int t = threadIdx.x;
    if (t < 64) {
        const int* ei32 = (const int*)ei;
        int nz = (ei32[2 * t + 1] != 0) | (ei32[2 * (t + 64) + 1] != 0);
        unsigned long long bl = __ballot(nz);
        if (t == 0) sflag = (bl == 0ULL) ? 1 : 0;
    }
    for (int b = t; b < NBMAX; b += 512) lhist[b] = 0;
    __syncthreads();
    bool w64 = sflag != 0;
    int chunk = (E + gridDim.x - 1) / gridDim.x;
    int cs = blockIdx.x * chunk;
    int ce = cs + chunk; if (ce > E) ce = E;
    for (int i = cs + t; i < ce; i += 512) {
        int d = w64 ? (int)((const long long*)ei)[E + i] : ((const int*)ei)[E + i];
        int j = i - cs;
        if (j < CHUNKMAX) dcache[j] = d;
        atomicAdd(&lhist[d >> 6], 1);
    }
    __syncthreads();
    for (int b = t; b < NB; b += 512) {
        int c = lhist[b];
        if (c) lbase[b] = b * SLACK + atomicAdd(&bcnt[b], c);
        lhist[b] = 0;  // reuse as local cursor
    }
    __syncthreads();
    for (int i = cs + t; i < ce; i += 512) {
        int s = w64 ? (int)((const long long*)ei)[i] : ((const int*)ei)[i];
        int j = i - cs;
        int d = (j < CHUNKMAX) ? dcache[j]
                               : (w64 ? (int)((const long long*)ei)[E + i] : ((const int*)ei)[E + i]);
        int b = d >> 6;
        int p = lbase[b] + atomicAdd(&lhist[b], 1);
        binned[p] = (s << 6) | (d & 63);
    }
}

// Sort within bucket (block-per-bucket). Inline exclusive prefix over bcnt[0..b) (L2-hot).
// LDS 64-counter histogram + wave scan produce exact CSR, off[v], dinv[v]=rsqrt(deg+1).
__global__ __launch_bounds__(256) void sort_kernel(const int* __restrict__ binned,
                                                   const int* __restrict__ bcnt, int N, int E,
                                                   int* __restrict__ off, float* __restrict__ dinv,
                                                   int* __restrict__ csr) {
    __shared__ int hist[BKT];
    __shared__ int cur[BKT];
    __shared__ int pred[4];
    int t = threadIdx.x;
    int b = blockIdx.x;
    int v0 = b * BKT;
    int part = 0;
    for (int j = t; j < b; j += 256) part += bcnt[j];
#pragma unroll
    for (int o = 32; o > 0; o >>= 1) part += __shfl_down(part, o, 64);
    if ((t & 63) == 0) pred[t >> 6] = part;
    if (t < BKT) hist[t] = 0;
    __syncthreads();
    int base = pred[0] + pred[1] + pred[2] + pred[3];
    int cnt_b = bcnt[b];                 // broadcast load
    int si = b * SLACK, ei_ = si + cnt_b;
    for (int i = si + t; i < ei_; i += 256) atomicAdd(&hist[binned[i] & 63], 1);
    __syncthreads();
    if (t < 64) {                        // wave 0: exclusive scan of 64 counters
        int c = hist[t];
        int sc = c;
#pragma unroll
        for (int o = 1; o < 64; o <<= 1) {
            int y = __shfl_up(sc, o, 64);
            if (t >= o) sc += y;
        }
        int start = base + sc - c;
        cur[t] = start;
        int v = v0 + t;
        if (v < N) {
            off[v] = start;
            dinv[v] = rsqrtf((float)(c + 1));
        }
    }
    if (b == 0 && t == 64) off[N] = E;
    __syncthreads();
    for (int i = si + t; i < ei_; i += 256) {
        int a = binned[i];
        int p = atomicAdd(&cur[a & 63], 1);
        csr[p] = a >> 6;
    }
}

// g1 = fp16( dinv ⊙ (x @ W1) ).  W-in-registers: each lane owns W column `lane`
// (128 statically-indexed VGPRs). x rows staged in LDS, read as wave-uniform b128
// broadcasts -> FMA-bound. fp16 store halves gather-phase traffic.
__global__ __launch_bounds__(256) void gemm1_kernel(const float* __restrict__ x, const float* __restrict__ W1,
                                                    const float* __restrict__ dinv, __half* __restrict__ g1, int N) {
    __shared__ float xs[BM * IN_DIM];    // 32 KB = 2048 float4
    int t = threadIdx.x;
    int lane = t & 63, wv = t >> 6;
    int row0 = blockIdx.x * BM;
    float wreg[IN_DIM];
#pragma unroll
    for (int k = 0; k < IN_DIM; ++k) wreg[k] = W1[k * HID + lane];   // coalesced 256B/instr
#pragma unroll
    for (int p = 0; p < 8; ++p) {
        int id = t + 256 * p;            // id = r*32 + g
        int r = id >> 5, g = id & 31;
        float4 v = make_float4(0.f, 0.f, 0.f, 0.f);
        int gr = row0 + r;
        if (gr < N) v = ((const float4*)x)[(size_t)gr * (IN_DIM / 4) + g];
        ((float4*)xs)[id] = v;
    }
    __syncthreads();
    const float4* xs4 = (const float4*)xs;
    for (int rr = 0; rr < 16; ++rr) {
        int r = wv * 16 + rr;
        float acc = 0.f;
#pragma unroll
        for (int k4 = 0; k4 < 32; ++k4) {
            float4 xv = xs4[r * 32 + k4];            // wave-uniform broadcast
            acc = fmaf(xv.x, wreg[4 * k4 + 0], acc);
            acc = fmaf(xv.y, wreg[4 * k4 + 1], acc);
            acc = fmaf(xv.z, wreg[4 * k4 + 2], acc);
            acc = fmaf(xv.w, wreg[4 * k4 + 3], acc);
        }
        int gr = row0 + r;
        if (gr < N) g1[(size_t)gr * HID + lane] = __float2half(dinv[gr] * acc);
    }
}

// Layer-1 aggregation (one wave per node, lane = feature) fused with
// relu + (h1 @ W2) wave-reduction -> g2[v] = dinv[v] * (relu(out1) @ W2)
// fp16 rows: 128B per edge; int4 broadcast index loads; 8 rows in flight.
__global__ __launch_bounds__(256) void gather1_kernel(const __half* __restrict__ g1, const int* __restrict__ off,
                                                      const int* __restrict__ csr, const float* __restrict__ dinv,
                                                      const float* __restrict__ b1, const float* __restrict__ W2,
                                                      float* __restrict__ g2, int N) {
    int wid = threadIdx.x >> 6;
    int lane = threadIdx.x & 63;
    int v = blockIdx.x * 4 + wid;
    if (v >= N) return;
    int s = off[v], e = off[v + 1];
    float acc = __half2float(g1[(size_t)v * HID + lane]);      // self loop
    int i = s;
    while (i < e && (i & 3)) { acc += __half2float(g1[(size_t)csr[i] * HID + lane]); ++i; }
    for (; i + 8 <= e; i += 8) {
        int4 a = *(const int4*)(csr + i);
        int4 b = *(const int4*)(csr + i + 4);
        float f0 = __half2float(g1[(size_t)a.x * HID + lane]);
        float f1 = __half2float(g1[(size_t)a.y * HID + lane]);
        float f2 = __half2float(g1[(size_t)a.z * HID + lane]);
        float f3 = __half2float(g1[(size_t)a.w * HID + lane]);
        float f4 = __half2float(g1[(size_t)b.x * HID + lane]);
        float f5 = __half2float(g1[(size_t)b.y * HID + lane]);
        float f6 = __half2float(g1[(size_t)b.z * HID + lane]);
        float f7 = __half2float(g1[(size_t)b.w * HID + lane]);
        acc += ((f0 + f1) + (f2 + f3)) + ((f4 + f5) + (f6 + f7));
    }
    if (i + 4 <= e) {
        int4 a = *(const int4*)(csr + i);
        float f0 = __half2float(g1[(size_t)a.x * HID + lane]);
        float f1 = __half2float(g1[(size_t)a.y * HID + lane]);
        float f2 = __half2float(g1[(size_t)a.z * HID + lane]);
        float f3 = __half2float(g1[(size_t)a.w * HID + lane]);
        acc += (f0 + f1) + (f2 + f3);
        i += 4;
    }
    for (; i < e; ++i) acc += __half2float(g1[(size_t)csr[i] * HID + lane]);
    float dv = dinv[v];
    float h = fmaxf(fmaf(dv, acc, b1[lane]), 0.0f);   // out1 = dinv*acc + b1, relu
    float p = h * W2[lane];
#pragma unroll
    for (int o = 32; o > 0; o >>= 1) p += __shfl_down(p, o, 64);
    if (lane == 0) g2[v] = dv * p;
}

// Layer-2 aggregation on scalars: out[v] = dinv[v]*(g2[v] + sum g2[u]) + b2
__global__ __launch_bounds__(256) void gather2_kernel(const float* __restrict__ g2, const int* __restrict__ off,
                                                      const int* __restrict__ csr, const float* __restrict__ dinv,
                                                      const float* __restrict__ b2, float* __restrict__ out, int N) {
    int wid = threadIdx.x >> 6;
    int lane = threadIdx.x & 63;
    int v = blockIdx.x * 4 + wid;
    if (v >= N) return;
    int s = off[v], e = off[v + 1];
    float p = 0.f;
    for (int i = s + lane; i < e; i += 64) p += g2[csr[i]];
#pragma unroll
    for (int o = 32; o > 0; o >>= 1) p += __shfl_down(p, o, 64);
    if (lane == 0) out[v] = fmaf(dinv[v], g2[v] + p, b2[0]);
}

extern "C" void kernel_launch(void* const* d_in, const int* in_sizes, int n_in,
                              void* d_out, int out_size, void* d_ws, size_t ws_size,
                              hipStream_t stream) {
    const float* x  = (const float*)d_in[0];
    const void*  ei = d_in[1];
    const float* W1 = (const float*)d_in[2];
    const float* b1 = (const float*)d_in[3];
    const float* W2 = (const float*)d_in[4];
    const float* b2 = (const float*)d_in[5];
    float* out = (float*)d_out;

    int N = in_sizes[0] / IN_DIM;
    int E = in_sizes[1] / 2;
    int NB = (N + BKT - 1) / BKT;   // 782 for N=50000 (<= NBMAX)

    char* w = (char*)d_ws;
    size_t o = 0;
    auto alloc = [&](size_t bytes) { char* p = w + o; o = (o + bytes + 255) & ~(size_t)255; return p; };
    int*    bcnt   = (int*)   alloc((size_t)NBMAX * sizeof(int));
    int*    off    = (int*)   alloc((size_t)(N + 1) * sizeof(int));
    float*  dinv   = (float*) alloc((size_t)N * sizeof(float));
    int*    binned = (int*)   alloc((size_t)NB * SLACK * sizeof(int));
    int*    csr    = (int*)   alloc((size_t)E * sizeof(int));
    __half* g1     = (__half*)alloc((size_t)N * HID * sizeof(__half));
    float*  g2     = (float*) alloc((size_t)N * sizeof(float));
    (void)ws_size; (void)n_in; (void)out_size;

    hipMemsetAsync(bcnt, 0, (size_t)NBMAX * sizeof(int), stream);
    bin_kernel<<<256, 512, 0, stream>>>(ei, E, NB, bcnt, binned);
    sort_kernel<<<NB, 256, 0, stream>>>(binned, bcnt, N, E, off, dinv, csr);
    gemm1_kernel<<<(N + BM - 1) / BM, 256, 0, stream>>>(x, W1, dinv, g1, N);
    gather1_kernel<<<(N + 3) / 4, 256, 0, stream>>>(g1, off, csr, dinv, b1, W2, g2, N);
    gather2_kernel<<<(N + 3) / 4, 256, 0, stream>>>(g2, off, csr, dinv, b2, out, N);
}